// Round 3
// baseline (619.585 us; speedup 1.0000x reference)
//
#include <hip/hip_runtime.h>

typedef unsigned short bfraw;
typedef __attribute__((ext_vector_type(8))) short short8;
typedef __attribute__((ext_vector_type(4))) float f32x4;

__device__ __forceinline__ float b2f(bfraw u){ return __uint_as_float(((unsigned int)u)<<16); }
__device__ __forceinline__ bfraw f2b(float f){
  unsigned int u = __float_as_uint(f);
  return (bfraw)((u + 0x7FFFu + ((u>>16)&1u)) >> 16);
}
__device__ __forceinline__ void store_out(float* p, float v){ *p = v; }
__device__ __forceinline__ void store_out(bfraw* p, float v){ *p = f2b(v); }
__device__ __forceinline__ void gload_lds16(const bfraw* g, short* l) {
  __builtin_amdgcn_global_load_lds((const __attribute__((address_space(1))) void*)g,
                                   (__attribute__((address_space(3))) void*)l, 16, 0, 0);
}
// packs bf16(a) into low 16, bf16(b) into high 16 (RNE) — single VALU op
__device__ __forceinline__ unsigned int cvt_pk_bf16(float a, float b) {
  unsigned int r;
  asm("v_cvt_pk_bf16_f32 %0, %1, %2" : "=v"(r) : "v"(a), "v"(b));
  return r;
}
__device__ __forceinline__ void waitvm4(){ asm volatile("s_waitcnt vmcnt(4)" ::: "memory"); }
__device__ __forceinline__ void waitvm0(){ asm volatile("s_waitcnt vmcnt(0)" ::: "memory"); }
__device__ __forceinline__ void fence_bar(){
  __builtin_amdgcn_sched_barrier(0);
  __builtin_amdgcn_s_barrier();
  __builtin_amdgcn_sched_barrier(0);
}

// ---------------- transpose + convert: out[C][R] = bf16(in[R][C]), in fp32 ------
__global__ __launch_bounds__(1024) void transpose_f32_bf16(const float* __restrict__ in,
                                                           bfraw* __restrict__ out,
                                                           int R, int C) {
  __shared__ bfraw tile[64][65];
  const int tx = threadIdx.x, ty = threadIdx.y;
  const int c0 = blockIdx.x*64, r0 = blockIdx.y*64;
  #pragma unroll
  for (int u = 0; u < 4; ++u)
    tile[ty + u*16][tx] = f2b(in[(size_t)(r0 + ty + u*16)*C + c0 + tx]);
  __syncthreads();
  #pragma unroll
  for (int u = 0; u < 4; ++u)
    out[(size_t)(c0 + ty + u*16)*R + r0 + tx] = tile[tx][ty + u*16];
}

// ---------------- layernorm over D=1024: fp32 in, fp32 params, bf16 out ----------
__global__ __launch_bounds__(256) void ln_kernel(const float* __restrict__ x,
                                                 const float* __restrict__ g,
                                                 const float* __restrict__ b,
                                                 bfraw* __restrict__ out) {
  const int row = blockIdx.x, tid = threadIdx.x;
  const f32x4 v = ((const f32x4*)(x + (size_t)row*1024))[tid];
  float s  = v[0]+v[1]+v[2]+v[3];
  float s2 = v[0]*v[0]+v[1]*v[1]+v[2]*v[2]+v[3]*v[3];
  #pragma unroll
  for (int off = 1; off < 64; off <<= 1) { s += __shfl_xor(s, off); s2 += __shfl_xor(s2, off); }
  __shared__ float red[8];
  const int wv = tid>>6, ln_ = tid&63;
  if (ln_ == 0) { red[wv] = s; red[4+wv] = s2; }
  __syncthreads();
  float a  = red[0]+red[1]+red[2]+red[3];
  float a2 = red[4]+red[5]+red[6]+red[7];
  float mean = a*(1.0f/1024.0f);
  float var  = a2*(1.0f/1024.0f) - mean*mean;
  float inv  = rsqrtf(var + 1e-5f);
  const f32x4 gr = ((const f32x4*)g)[tid];
  const f32x4 br = ((const f32x4*)b)[tid];
  ushort4 o4;
  o4.x = f2b((v[0]-mean)*inv*gr[0] + br[0]);
  o4.y = f2b((v[1]-mean)*inv*gr[1] + br[1]);
  o4.z = f2b((v[2]-mean)*inv*gr[2] + br[2]);
  o4.w = f2b((v[3]-mean)*inv*gr[3] + br[3]);
  ((ushort4*)(out + (size_t)row*1024))[tid] = o4;
}

// ---------------- 256x256 GEMM, BK=64, 8 waves, 4-phase counted-vmcnt pipeline ----
// C[M,N] = A[M,K] * Bt[N,K]^T (+epilogue). Requires M%256==0, N%256==0, K%64==0,
// grid size divisible by 8 (XCD swizzle bijectivity).
// LDS per matrix: [2 buf][2 k-slab][256 rows][4 chunks x 16B] bf16 (16 KiB slabs,
// linear dest for global_load_lds). Chunk swizzle: stored chunk ch holds global
// chunk ch ^ P(row), P(row) = (row&3)^((row>>2)&1) — applied to the GLOBAL SOURCE
// at stage time and to the ds_read chunk index (involution; rule #21). All
// fragment rows rr have rr&7 == r&7, so P(rr) is computable from lane r alone.
// Race discipline (m201 ordering): counted vmcnt waits sit at the END of phases
// 1 and 3 — each wave drains its own counter, THEN the barrier publishes all
// waves' landings, THEN the next phase's ds_reads touch the new slab. vmcnt
// never drains to 0 in steady state (T4).
// EPI: 0 = none, 1 = +bias +resid, 2 = +bias +exact GELU
template<int EPI, typename OutT>
__global__ __launch_bounds__(512, 2) void gemm256(const bfraw* __restrict__ A,
                                                  const bfraw* __restrict__ Bt,
                                                  const float* __restrict__ bias,
                                                  const float* __restrict__ resid,
                                                  OutT* __restrict__ C,
                                                  int M, int N, int K) {
  __shared__ __align__(16) short As[2*2*8192];   // 64 KiB
  __shared__ __align__(16) short Bs[2*2*8192];   // 64 KiB
  const int tid = threadIdx.x;
  const int wv = tid>>6, lane = tid&63;
  const int wm = wv>>2, wn = wv&3;               // 2M x 4N waves
  const int q_ = lane>>4, r = lane&15;
  // --- bijective XCD swizzle (nwg % 8 == 0 by launch shapes) ---
  const int nbm = M>>8, nbn = N>>8;
  const int nwg = nbm*nbn;
  int id = (int)blockIdx.x;
  id = (id&7)*(nwg>>3) + (id>>3);
  const int bm = id % nbm, bn = id / nbm;

  // --- staging geometry: chunk c = i*512 + tid (i=0,1); row=c>>2, ch=c&3 ---
  const int srow = tid>>2, sch = tid&3;
  const int sP   = (srow&3) ^ ((srow>>2)&1);            // row swizzle pattern
  const int se   = ((sch ^ sP) << 3);                   // pre-swizzled source col
  const bfraw* Ag = A  + (size_t)(bm*256 + srow)*K + se;
  const bfraw* Bg = Bt + (size_t)(bn*256 + srow)*K + se;
  const size_t rowstep = (size_t)128*K;                 // i=1: +128 rows (same swz)

  auto stageA = [&](int s, int k1, int nb) {
    const bfraw* g = Ag + k1 + s*32;
    short* d = As + (nb*2+s)*8192 + tid*8;
    gload_lds16(g, d);
    gload_lds16(g + rowstep, d + 4096);
  };
  auto stageB = [&](int s, int k1, int nb) {
    const bfraw* g = Bg + k1 + s*32;
    short* d = Bs + (nb*2+s)*8192 + tid*8;
    gload_lds16(g, d);
    gload_lds16(g + rowstep, d + 4096);
  };

  // --- fragment read offsets (within a 256x32 slab, shorts) ---
  const int xsw = ((q_ ^ (r&3) ^ ((r>>2)&1)) << 3);     // swizzled chunk*8
  const int axo = (wm*128 + r)*32 + xsw;                // + mi*512
  const int bxo = (wn*64  + r)*32 + xsw;                // + ni*512

  f32x4 acc[8][4];
  #pragma unroll
  for (int mi = 0; mi < 8; ++mi)
    #pragma unroll
    for (int ni = 0; ni < 4; ++ni)
      acc[mi][ni] = (f32x4){0.f, 0.f, 0.f, 0.f};

  // prologue: stage tile 0 (order A0,B0,A1,B1) into buf 0; publish s0.
  stageA(0, 0, 0); stageB(0, 0, 0); stageA(1, 0, 0); stageB(1, 0, 0);
  waitvm4();                 // own A0,B0 landed (A1,B1 still in flight)
  fence_bar();               // all waves' A0,B0 now visible

  const int ntiles = K >> 6;
  short8 af[4], bf[4];
  for (int t = 0; t < ntiles; ++t) {
    const int buf = t & 1, nb = buf ^ 1;
    const int k1 = (t + 1) << 6;
    const bool more = (t + 1) < ntiles;

    // ---- phase 0: ks=0, mi 0..3 ----
    {
      const short* Ab = As + (buf*2+0)*8192;
      const short* Bb = Bs + (buf*2+0)*8192;
      #pragma unroll
      for (int ni = 0; ni < 4; ++ni) bf[ni] = *(const short8*)&Bb[bxo + ni*512];
      #pragma unroll
      for (int m = 0; m < 4; ++m)   af[m]  = *(const short8*)&Ab[axo + m*512];
    }
    if (more) stageA(0, k1, nb);
    fence_bar();
    __builtin_amdgcn_s_setprio(1);
    #pragma unroll
    for (int m = 0; m < 4; ++m)
      #pragma unroll
      for (int ni = 0; ni < 4; ++ni)
        acc[m][ni] = __builtin_amdgcn_mfma_f32_16x16x32_bf16(af[m], bf[ni], acc[m][ni], 0, 0, 0);
    __builtin_amdgcn_s_setprio(0);
    fence_bar();

    // ---- phase 1: ks=0, mi 4..7 (bf reused) ----
    {
      const short* Ab = As + (buf*2+0)*8192;
      #pragma unroll
      for (int m = 0; m < 4; ++m) af[m] = *(const short8*)&Ab[axo + (4+m)*512];
    }
    if (more) stageB(0, k1, nb);
    if (more) waitvm4(); else waitvm0();   // this tile's s1 halves landed (own)
    fence_bar();                           // ...and published to all waves
    __builtin_amdgcn_s_setprio(1);
    #pragma unroll
    for (int m = 0; m < 4; ++m)
      #pragma unroll
      for (int ni = 0; ni < 4; ++ni)
        acc[4+m][ni] = __builtin_amdgcn_mfma_f32_16x16x32_bf16(af[m], bf[ni], acc[4+m][ni], 0, 0, 0);
    __builtin_amdgcn_s_setprio(0);
    fence_bar();

    // ---- phase 2: ks=1, mi 0..3 ----
    {
      const short* Ab = As + (buf*2+1)*8192;
      const short* Bb = Bs + (buf*2+1)*8192;
      #pragma unroll
      for (int ni = 0; ni < 4; ++ni) bf[ni] = *(const short8*)&Bb[bxo + ni*512];
      #pragma unroll
      for (int m = 0; m < 4; ++m)   af[m]  = *(const short8*)&Ab[axo + m*512];
    }
    if (more) stageA(1, k1, nb);
    fence_bar();
    __builtin_amdgcn_s_setprio(1);
    #pragma unroll
    for (int m = 0; m < 4; ++m)
      #pragma unroll
      for (int ni = 0; ni < 4; ++ni)
        acc[m][ni] = __builtin_amdgcn_mfma_f32_16x16x32_bf16(af[m], bf[ni], acc[m][ni], 0, 0, 0);
    __builtin_amdgcn_s_setprio(0);
    fence_bar();

    // ---- phase 3: ks=1, mi 4..7 ----
    {
      const short* Ab = As + (buf*2+1)*8192;
      #pragma unroll
      for (int m = 0; m < 4; ++m) af[m] = *(const short8*)&Ab[axo + (4+m)*512];
    }
    if (more) stageB(1, k1, nb);
    if (more) waitvm4();                   // next tile's s0 halves landed (own)
    fence_bar();                           // ...and published to all waves
    __builtin_amdgcn_s_setprio(1);
    #pragma unroll
    for (int m = 0; m < 4; ++m)
      #pragma unroll
      for (int ni = 0; ni < 4; ++ni)
        acc[4+m][ni] = __builtin_amdgcn_mfma_f32_16x16x32_bf16(af[m], bf[ni], acc[4+m][ni], 0, 0, 0);
    __builtin_amdgcn_s_setprio(0);
    fence_bar();
  }

  // ---- epilogue (register-only inputs; no LDS) ----
  #pragma unroll
  for (int mi = 0; mi < 8; ++mi) {
    #pragma unroll
    for (int ni = 0; ni < 4; ++ni) {
      const int gcol = bn*256 + wn*64 + ni*16 + r;
      float bv = 0.f;
      if constexpr (EPI != 0) bv = bias[gcol];
      #pragma unroll
      for (int rg = 0; rg < 4; ++rg) {
        const int grow = bm*256 + wm*128 + mi*16 + q_*4 + rg;
        float val = acc[mi][ni][rg];
        if constexpr (EPI != 0) val += bv;
        if constexpr (EPI == 2) val = 0.5f*val*(1.0f + erff(val*0.70710678118654752f));
        if constexpr (EPI == 1) val += resid[(size_t)grow*N + gcol];
        store_out(&C[(size_t)grow*N + gcol], val);
      }
    }
  }
}

// ---------------- MFMA flash attention (causal), T=2048, HD=64, scale=1/8 ---------
// (unchanged from round 1: S^T orientation, scalar softmax state, cvt_pk P-pack)
__global__ __launch_bounds__(256) void flash_attn(const bfraw* __restrict__ qkv,
                                                  bfraw* __restrict__ o) {
  __shared__ __align__(16) short Ksh[4096];
  __shared__ __align__(16) short Vts[4096];
  __shared__ __align__(16) short Psh[4096];
  const int tid = threadIdx.x;
  const int w = tid >> 6, lane = tid & 63;
  const int r = lane & 15, qd = lane >> 4;
  const int bb = blockIdx.y >> 4, h = blockIdx.y & 15;
  const size_t hb = (size_t)bb * 2048;
  short* Pw = &Psh[w * 1024];
  const int f0 = tid, f1 = tid + 256;
  const int key0 = f0 >> 3, dc0 = (f0 & 7) * 8;
  const int key1 = f1 >> 3, dc1 = (f1 & 7) * 8;

  for (int pass = 0; pass < 2; ++pass) {
    const int qt = pass ? (31 - (int)blockIdx.x) : (int)blockIdx.x;
    const int q0 = qt * 64;
    const int ntile = qt + 1;

    short8 qf[2];
    {
      const bfraw* qrow = qkv + (hb + q0 + w*16 + r) * 3072 + h*64;
      qf[0] = *(const short8*)(qrow + qd*8);
      qf[1] = *(const short8*)(qrow + qd*8 + 32);
    }

    f32x4 oacc[4];
    #pragma unroll
    for (int nt = 0; nt < 4; ++nt) oacc[nt] = (f32x4){0.f,0.f,0.f,0.f};
    float m_i = -3.0e38f;
    float l_i = 0.f;

    short8 kpre[2], vpre[2];
    {
      const bfraw* b0 = qkv + (hb + key0) * 3072 + h*64 + dc0;
      const bfraw* b1 = qkv + (hb + key1) * 3072 + h*64 + dc1;
      kpre[0] = *(const short8*)(b0 + 1024); vpre[0] = *(const short8*)(b0 + 2048);
      kpre[1] = *(const short8*)(b1 + 1024); vpre[1] = *(const short8*)(b1 + 2048);
    }

    for (int t = 0; t < ntile; ++t) {
      __syncthreads();
      #pragma unroll
      for (int pz = 0; pz < 2; ++pz) {
        const int key = pz ? key1 : key0, dc = pz ? dc1 : dc0;
        *(short8*)&Ksh[key*64 + ((((dc>>3) ^ (key>>3)) & 7) << 3)] = kpre[pz];
        const int kg = key >> 3, k7 = key & 7, dg = dc >> 3;
        #pragma unroll
        for (int i2 = 0; i2 < 8; ++i2)
          Vts[(dc + i2)*64 + (((kg ^ dg) & 7) << 3) + k7] = vpre[pz][i2];
      }
      __syncthreads();
      if (t + 1 < ntile) {
        const int j0n = (t + 1) * 64;
        const bfraw* b0 = qkv + (hb + j0n + key0) * 3072 + h*64 + dc0;
        const bfraw* b1 = qkv + (hb + j0n + key1) * 3072 + h*64 + dc1;
        kpre[0] = *(const short8*)(b0 + 1024); vpre[0] = *(const short8*)(b0 + 2048);
        kpre[1] = *(const short8*)(b1 + 1024); vpre[1] = *(const short8*)(b1 + 2048);
      }

      f32x4 s4[4];
      __builtin_amdgcn_s_setprio(1);
      #pragma unroll
      for (int kt = 0; kt < 4; ++kt) {
        f32x4 a = (f32x4){0.f,0.f,0.f,0.f};
        const int key = kt*16 + r, kgk = key >> 3;
        #pragma unroll
        for (int ks = 0; ks < 2; ++ks) {
          short8 kf8 = *(const short8*)&Ksh[key*64 + ((((qd + ks*4) ^ kgk) & 7) << 3)];
          a = __builtin_amdgcn_mfma_f32_16x16x32_bf16(kf8, qf[ks], a, 0, 0, 0);
        }
        s4[kt] = a;
      }
      __builtin_amdgcn_s_setprio(0);

      const bool diag = (t == qt);
      #pragma unroll
      for (int kt = 0; kt < 4; ++kt)
        #pragma unroll
        for (int rg = 0; rg < 4; ++rg) {
          float v = s4[kt][rg] * 0.125f;
          if (diag && (kt*16 + qd*4 + rg > w*16 + r)) v = -3.0e38f;
          s4[kt][rg] = v;
        }

      float mx = s4[0][0];
      #pragma unroll
      for (int kt = 0; kt < 4; ++kt)
        #pragma unroll
        for (int rg = 0; rg < 4; ++rg) mx = fmaxf(mx, s4[kt][rg]);
      mx = fmaxf(mx, __shfl_xor(mx, 16));
      mx = fmaxf(mx, __shfl_xor(mx, 32));
      const float mn = fmaxf(m_i, mx);
      const float alpha = __expf(m_i - mn);
      m_i = mn;
      l_i *= alpha;

      float lsum = 0.f;
      #pragma unroll
      for (int kt = 0; kt < 4; ++kt) {
        const float p0 = __expf(s4[kt][0] - mn);
        const float p1 = __expf(s4[kt][1] - mn);
        const float p2 = __expf(s4[kt][2] - mn);
        const float p3 = __expf(s4[kt][3] - mn);
        lsum += (p0 + p1) + (p2 + p3);
        uint2 pk;
        pk.x = cvt_pk_bf16(p0, p1);
        pk.y = cvt_pk_bf16(p2, p3);
        *(uint2*)((char*)Pw + r*128 + ((((kt*2 + (qd>>1)) ^ (r&7)) & 7) << 4) + ((qd&1)<<3)) = pk;
      }
      lsum += __shfl_xor(lsum, 16);
      lsum += __shfl_xor(lsum, 32);
      l_i += lsum;
      #pragma unroll
      for (int nt = 0; nt < 4; ++nt)
        #pragma unroll
        for (int rg = 0; rg < 4; ++rg) oacc[nt][rg] *= alpha;

      short8 pf[2];
      #pragma unroll
      for (int ks = 0; ks < 2; ++ks)
        pf[ks] = *(const short8*)&Pw[r*64 + ((((qd + ks*4) ^ (r & 7)) & 7) << 3)];
      __builtin_amdgcn_s_setprio(1);
      #pragma unroll
      for (int nt = 0; nt < 4; ++nt) {
        const int d = nt*16 + r, dg = d >> 3;
        #pragma unroll
        for (int ks = 0; ks < 2; ++ks) {
          short8 vf = *(const short8*)&Vts[d*64 + ((((qd + ks*4) ^ dg) & 7) << 3)];
          oacc[nt] = __builtin_amdgcn_mfma_f32_16x16x32_bf16(vf, pf[ks], oacc[nt], 0, 0, 0);
        }
      }
      __builtin_amdgcn_s_setprio(0);
    }

    const float invl = 1.0f / l_i;
    bfraw* orow = o + (hb + q0 + w*16 + r) * 1024 + h*64;
    #pragma unroll
    for (int nt = 0; nt < 4; ++nt) {
      uint2 ov;
      ov.x = cvt_pk_bf16(oacc[nt][0]*invl, oacc[nt][1]*invl);
      ov.y = cvt_pk_bf16(oacc[nt][2]*invl, oacc[nt][3]*invl);
      *(uint2*)(orow + nt*16 + qd*4) = ov;
    }
  }
}

// ---------------- host ----------------
extern "C" void kernel_launch(void* const* d_in, const int* in_sizes, int n_in,
                              void* d_out, int out_size, void* d_ws, size_t ws_size,
                              hipStream_t stream) {
  (void)in_sizes; (void)n_in;
  const float* x    = (const float*)d_in[0];
  // d_in[1] = causal mask (int32) -- deterministic tril, handled analytically
  const float* ln1g = (const float*)d_in[2];
  const float* ln1b = (const float*)d_in[3];
  const float* ln2g = (const float*)d_in[4];
  const float* ln2b = (const float*)d_in[5];
  const float* qkvw = (const float*)d_in[6];
  const float* outw = (const float*)d_in[7];
  const float* outb = (const float*)d_in[8];
  const float* fc1w = (const float*)d_in[9];
  const float* fc1b = (const float*)d_in[10];
  const float* fc2w = (const float*)d_in[11];
  const float* fc2b = (const float*)d_in[12];
  float* out = (float*)d_out;   // reference output dtype = float32

  char* ws = (char*)d_ws;
  size_t off = 0;
  auto alloc = [&](size_t bytes) -> void* { void* p = ws + off; off += (bytes + 255) & ~(size_t)255; return p; };
  bfraw* wt_qkv = (bfraw*)alloc(3072ULL*1024*2);
  bfraw* wt_out = (bfraw*)alloc(1024ULL*1024*2);
  bfraw* wt_fc1 = (bfraw*)alloc(4096ULL*1024*2);
  bfraw* wt_fc2 = (bfraw*)alloc(1024ULL*4096*2);
  bfraw* hbuf   = (bfraw*)alloc(8192ULL*1024*2);
  float* x1     = (float*)alloc(8192ULL*1024*4);
  char*  big    = (char*) alloc(8192ULL*3072*2 + 8192ULL*1024*2);
  bfraw* qkv  = (bfraw*)big;
  bfraw* obuf = (bfraw*)(big + 8192ULL*3072*2);
  bfraw* hf   = (bfraw*)big;

  if (off > ws_size) {
    (void)hipMemsetAsync(d_out, 0x7F, (size_t)out_size*4, stream);
    return;
  }

  dim3 tb(64, 16);
  transpose_f32_bf16<<<dim3(48, 16), tb, 0, stream>>>(qkvw, wt_qkv, 1024, 3072);
  transpose_f32_bf16<<<dim3(16, 16), tb, 0, stream>>>(outw, wt_out, 1024, 1024);
  transpose_f32_bf16<<<dim3(64, 16), tb, 0, stream>>>(fc1w, wt_fc1, 1024, 4096);
  transpose_f32_bf16<<<dim3(16, 64), tb, 0, stream>>>(fc2w, wt_fc2, 4096, 1024);

  ln_kernel<<<8192, 256, 0, stream>>>(x, ln1g, ln1b, hbuf);
  gemm256<0, bfraw><<<dim3(384), 512, 0, stream>>>(hbuf, wt_qkv, nullptr, nullptr, qkv, 8192, 3072, 1024);
  flash_attn<<<dim3(16, 64), 256, 0, stream>>>(qkv, obuf);
  gemm256<1, float><<<dim3(128), 512, 0, stream>>>(obuf, wt_out, outb, x, x1, 8192, 1024, 1024);
  ln_kernel<<<8192, 256, 0, stream>>>(x1, ln2g, ln2b, hbuf);
  gemm256<2, bfraw><<<dim3(512), 512, 0, stream>>>(hbuf, wt_fc1, fc1b, nullptr, hf, 8192, 4096, 1024);
  gemm256<1, float><<<dim3(128), 512, 0, stream>>>(hf, wt_fc2, fc2b, x1, out, 8192, 1024, 4096);
}

// Round 4
// 616.763 us; speedup vs baseline: 1.0046x; 1.0046x over previous
//
#include <hip/hip_runtime.h>

typedef unsigned short bfraw;
typedef __attribute__((ext_vector_type(8))) short short8;
typedef __attribute__((ext_vector_type(4))) float f32x4;

__device__ __forceinline__ float b2f(bfraw u){ return __uint_as_float(((unsigned int)u)<<16); }
__device__ __forceinline__ bfraw f2b(float f){
  unsigned int u = __float_as_uint(f);
  return (bfraw)((u + 0x7FFFu + ((u>>16)&1u)) >> 16);
}
__device__ __forceinline__ void store_out(float* p, float v){ *p = v; }
__device__ __forceinline__ void store_out(bfraw* p, float v){ *p = f2b(v); }
__device__ __forceinline__ void gload_lds16(const bfraw* g, short* l) {
  __builtin_amdgcn_global_load_lds((const __attribute__((address_space(1))) void*)g,
                                   (__attribute__((address_space(3))) void*)l, 16, 0, 0);
}
// packs bf16(a) into low 16, bf16(b) into high 16 (RNE) — single VALU op
__device__ __forceinline__ unsigned int cvt_pk_bf16(float a, float b) {
  unsigned int r;
  asm("v_cvt_pk_bf16_f32 %0, %1, %2" : "=v"(r) : "v"(a), "v"(b));
  return r;
}
__device__ __forceinline__ void waitvm3(){ asm volatile("s_waitcnt vmcnt(3)" ::: "memory"); }
__device__ __forceinline__ void waitvm0(){ asm volatile("s_waitcnt vmcnt(0)" ::: "memory"); }

// ---------------- transpose + convert: out[C][R] = bf16(in[R][C]), in fp32 ------
__global__ __launch_bounds__(1024) void transpose_f32_bf16(const float* __restrict__ in,
                                                           bfraw* __restrict__ out,
                                                           int R, int C) {
  __shared__ bfraw tile[64][65];
  const int tx = threadIdx.x, ty = threadIdx.y;
  const int c0 = blockIdx.x*64, r0 = blockIdx.y*64;
  #pragma unroll
  for (int u = 0; u < 4; ++u)
    tile[ty + u*16][tx] = f2b(in[(size_t)(r0 + ty + u*16)*C + c0 + tx]);
  __syncthreads();
  #pragma unroll
  for (int u = 0; u < 4; ++u)
    out[(size_t)(c0 + ty + u*16)*R + r0 + tx] = tile[tx][ty + u*16];
}

// ---------------- layernorm over D=1024: fp32 in, fp32 params, bf16 out ----------
__global__ __launch_bounds__(256) void ln_kernel(const float* __restrict__ x,
                                                 const float* __restrict__ g,
                                                 const float* __restrict__ b,
                                                 bfraw* __restrict__ out) {
  const int row = blockIdx.x, tid = threadIdx.x;
  const f32x4 v = ((const f32x4*)(x + (size_t)row*1024))[tid];
  float s  = v[0]+v[1]+v[2]+v[3];
  float s2 = v[0]*v[0]+v[1]*v[1]+v[2]*v[2]+v[3]*v[3];
  #pragma unroll
  for (int off = 1; off < 64; off <<= 1) { s += __shfl_xor(s, off); s2 += __shfl_xor(s2, off); }
  __shared__ float red[8];
  const int wv = tid>>6, ln_ = tid&63;
  if (ln_ == 0) { red[wv] = s; red[4+wv] = s2; }
  __syncthreads();
  float a  = red[0]+red[1]+red[2]+red[3];
  float a2 = red[4]+red[5]+red[6]+red[7];
  float mean = a*(1.0f/1024.0f);
  float var  = a2*(1.0f/1024.0f) - mean*mean;
  float inv  = rsqrtf(var + 1e-5f);
  const f32x4 gr = ((const f32x4*)g)[tid];
  const f32x4 br = ((const f32x4*)b)[tid];
  ushort4 o4;
  o4.x = f2b((v[0]-mean)*inv*gr[0] + br[0]);
  o4.y = f2b((v[1]-mean)*inv*gr[1] + br[1]);
  o4.z = f2b((v[2]-mean)*inv*gr[2] + br[2]);
  o4.w = f2b((v[3]-mean)*inv*gr[3] + br[3]);
  ((ushort4*)(out + (size_t)row*1024))[tid] = o4;
}

// ---------------- 256x128 GEMM, BK=64, 8 waves (4M x 2N), 2-phase counted vmcnt --
// C[M,N] = A[M,K] * Bt[N,K]^T (+epilogue). M%256==0, N%128==0, K%64==0, grid%8==0.
// Grids here: 768 / 256 / 1024 / 256 — all exact multiples of 256 CUs (no tail).
// LDS: A [2buf][2slab][256][32] = 64 KiB; B [2buf][2slab][128][32] = 32 KiB (96 KiB
// total -> 1 block/CU, 8 waves). Stage = 3 VMEM ops per slab (A:2, B:1), linear
// dest; chunk swizzle baked into the GLOBAL source and the ds_read chunk index
// (involution; rule #21). Counted-vmcnt discipline (m201 ordering): each phase
// ends with {stage next; vmcnt(3); s_barrier}; the wait covers the slab the NEXT
// phase reads; barrier publishes all waves' landings. Never drains to 0 in
// steady state (T4). NO sched_barrier(0) anywhere (m141 lesson).
// EPI: 0 = none, 1 = +bias +resid, 2 = +bias +exact GELU
template<int EPI, typename OutT>
__global__ __launch_bounds__(512, 2) void gemm_bn128(const bfraw* __restrict__ A,
                                                     const bfraw* __restrict__ Bt,
                                                     const float* __restrict__ bias,
                                                     const float* __restrict__ resid,
                                                     OutT* __restrict__ C,
                                                     int M, int N, int K) {
  __shared__ __align__(16) short As[2*2*8192];   // 64 KiB
  __shared__ __align__(16) short Bs[2*2*4096];   // 32 KiB
  const int tid = threadIdx.x;
  const int wv = tid>>6, lane = tid&63;
  const int wm = wv>>1, wn = wv&1;               // 4M x 2N waves, 64x64 each
  const int q_ = lane>>4, r = lane&15;
  // --- bijective XCD swizzle (nwg % 8 == 0 by launch shapes) ---
  const int nbm = M>>8, nbn = N>>7;
  const int nwg = nbm*nbn;
  int id = (int)blockIdx.x;
  id = (id&7)*(nwg>>3) + (id>>3);
  const int bm = id % nbm, bn = id / nbm;

  // --- staging: chunk c = tid (A also c = tid+512); row=c>>2, ch=c&3 ---
  const int srow = tid>>2, sch = tid&3;
  const int sP   = (srow&3) ^ ((srow>>2)&1);            // swizzle pattern P(row)
  const int se   = ((sch ^ sP) << 3);                   // pre-swizzled source col
  const bfraw* Ag = A  + (size_t)(bm*256 + srow)*K + se;
  const bfraw* Bg = Bt + (size_t)(bn*128 + srow)*K + se;
  const size_t rowstepA = (size_t)128*K;                // +128 rows, same P

  auto stage = [&](int s, int k0s, int nb) {            // 3 VMEM ops
    const bfraw* ga = Ag + k0s + s*32;
    short* da = As + (nb*2+s)*8192 + tid*8;
    gload_lds16(ga, da);
    gload_lds16(ga + rowstepA, da + 4096);
    const bfraw* gb = Bg + k0s + s*32;
    short* db = Bs + (nb*2+s)*4096 + tid*8;
    gload_lds16(gb, db);
  };

  // --- fragment read offsets (shorts, within a slab) ---
  const int xsw = ((q_ ^ (r&3) ^ ((r>>2)&1)) << 3);     // swizzled chunk*8
  const int axo = (wm*64 + r)*32 + xsw;                 // + mi*512
  const int bxo = (wn*64 + r)*32 + xsw;                 // + ni*512

  f32x4 acc[4][4];
  #pragma unroll
  for (int mi = 0; mi < 4; ++mi)
    #pragma unroll
    for (int ni = 0; ni < 4; ++ni)
      acc[mi][ni] = (f32x4){0.f, 0.f, 0.f, 0.f};

  // prologue: stage tile 0 slabs s0,s1 into buf 0 (6 loads); publish s0.
  stage(0, 0, 0); stage(1, 0, 0);
  waitvm3();                     // own s0 ops landed (s1 in flight)
  __builtin_amdgcn_s_barrier();  // all waves' s0 published

  const int ntiles = K >> 6;
  short8 af[4], bf[4];
  for (int t = 0; t < ntiles; ++t) {
    const int buf = t & 1, nb = buf ^ 1;
    const int k1 = (t + 1) << 6;
    const bool more = (t + 1) < ntiles;

    // ---- phase A: slab 0 ----
    {
      const short* Ab = As + (buf*2+0)*8192;
      const short* Bb = Bs + (buf*2+0)*4096;
      #pragma unroll
      for (int ni = 0; ni < 4; ++ni) bf[ni] = *(const short8*)&Bb[bxo + ni*512];
      #pragma unroll
      for (int m = 0; m < 4; ++m)   af[m]  = *(const short8*)&Ab[axo + m*512];
    }
    if (more) stage(0, k1, nb);
    if (more) waitvm3(); else waitvm0();   // this tile's s1 landed (own ops)
    __builtin_amdgcn_s_barrier();          // ...published to all waves
    __builtin_amdgcn_s_setprio(1);
    #pragma unroll
    for (int m = 0; m < 4; ++m)
      #pragma unroll
      for (int ni = 0; ni < 4; ++ni)
        acc[m][ni] = __builtin_amdgcn_mfma_f32_16x16x32_bf16(af[m], bf[ni], acc[m][ni], 0, 0, 0);
    __builtin_amdgcn_s_setprio(0);
    __builtin_amdgcn_s_barrier();

    // ---- phase B: slab 1 ----
    {
      const short* Ab = As + (buf*2+1)*8192;
      const short* Bb = Bs + (buf*2+1)*4096;
      #pragma unroll
      for (int ni = 0; ni < 4; ++ni) bf[ni] = *(const short8*)&Bb[bxo + ni*512];
      #pragma unroll
      for (int m = 0; m < 4; ++m)   af[m]  = *(const short8*)&Ab[axo + m*512];
    }
    if (more) { stage(1, k1, nb); waitvm3(); }  // next tile's s0 landed (own ops)
    __builtin_amdgcn_s_barrier();               // ...published to all waves
    __builtin_amdgcn_s_setprio(1);
    #pragma unroll
    for (int m = 0; m < 4; ++m)
      #pragma unroll
      for (int ni = 0; ni < 4; ++ni)
        acc[m][ni] = __builtin_amdgcn_mfma_f32_16x16x32_bf16(af[m], bf[ni], acc[m][ni], 0, 0, 0);
    __builtin_amdgcn_s_setprio(0);
    __builtin_amdgcn_s_barrier();
  }

  // ---- epilogue (register-only inputs; no LDS) ----
  #pragma unroll
  for (int mi = 0; mi < 4; ++mi) {
    #pragma unroll
    for (int ni = 0; ni < 4; ++ni) {
      const int gcol = bn*128 + wn*64 + ni*16 + r;
      float bv = 0.f;
      if constexpr (EPI != 0) bv = bias[gcol];
      #pragma unroll
      for (int rg = 0; rg < 4; ++rg) {
        const int grow = bm*256 + wm*64 + mi*16 + q_*4 + rg;
        float val = acc[mi][ni][rg];
        if constexpr (EPI != 0) val += bv;
        if constexpr (EPI == 2) val = 0.5f*val*(1.0f + erff(val*0.70710678118654752f));
        if constexpr (EPI == 1) val += resid[(size_t)grow*N + gcol];
        store_out(&C[(size_t)grow*N + gcol], val);
      }
    }
  }
}

// ---------------- MFMA flash attention (causal), T=2048, HD=64, scale=1/8 ---------
// (unchanged from round 1: S^T orientation, scalar softmax state, cvt_pk P-pack)
__global__ __launch_bounds__(256) void flash_attn(const bfraw* __restrict__ qkv,
                                                  bfraw* __restrict__ o) {
  __shared__ __align__(16) short Ksh[4096];
  __shared__ __align__(16) short Vts[4096];
  __shared__ __align__(16) short Psh[4096];
  const int tid = threadIdx.x;
  const int w = tid >> 6, lane = tid & 63;
  const int r = lane & 15, qd = lane >> 4;
  const int bb = blockIdx.y >> 4, h = blockIdx.y & 15;
  const size_t hb = (size_t)bb * 2048;
  short* Pw = &Psh[w * 1024];
  const int f0 = tid, f1 = tid + 256;
  const int key0 = f0 >> 3, dc0 = (f0 & 7) * 8;
  const int key1 = f1 >> 3, dc1 = (f1 & 7) * 8;

  for (int pass = 0; pass < 2; ++pass) {
    const int qt = pass ? (31 - (int)blockIdx.x) : (int)blockIdx.x;
    const int q0 = qt * 64;
    const int ntile = qt + 1;

    short8 qf[2];
    {
      const bfraw* qrow = qkv + (hb + q0 + w*16 + r) * 3072 + h*64;
      qf[0] = *(const short8*)(qrow + qd*8);
      qf[1] = *(const short8*)(qrow + qd*8 + 32);
    }

    f32x4 oacc[4];
    #pragma unroll
    for (int nt = 0; nt < 4; ++nt) oacc[nt] = (f32x4){0.f,0.f,0.f,0.f};
    float m_i = -3.0e38f;
    float l_i = 0.f;

    short8 kpre[2], vpre[2];
    {
      const bfraw* b0 = qkv + (hb + key0) * 3072 + h*64 + dc0;
      const bfraw* b1 = qkv + (hb + key1) * 3072 + h*64 + dc1;
      kpre[0] = *(const short8*)(b0 + 1024); vpre[0] = *(const short8*)(b0 + 2048);
      kpre[1] = *(const short8*)(b1 + 1024); vpre[1] = *(const short8*)(b1 + 2048);
    }

    for (int t = 0; t < ntile; ++t) {
      __syncthreads();
      #pragma unroll
      for (int pz = 0; pz < 2; ++pz) {
        const int key = pz ? key1 : key0, dc = pz ? dc1 : dc0;
        *(short8*)&Ksh[key*64 + ((((dc>>3) ^ (key>>3)) & 7) << 3)] = kpre[pz];
        const int kg = key >> 3, k7 = key & 7, dg = dc >> 3;
        #pragma unroll
        for (int i2 = 0; i2 < 8; ++i2)
          Vts[(dc + i2)*64 + (((kg ^ dg) & 7) << 3) + k7] = vpre[pz][i2];
      }
      __syncthreads();
      if (t + 1 < ntile) {
        const int j0n = (t + 1) * 64;
        const bfraw* b0 = qkv + (hb + j0n + key0) * 3072 + h*64 + dc0;
        const bfraw* b1 = qkv + (hb + j0n + key1) * 3072 + h*64 + dc1;
        kpre[0] = *(const short8*)(b0 + 1024); vpre[0] = *(const short8*)(b0 + 2048);
        kpre[1] = *(const short8*)(b1 + 1024); vpre[1] = *(const short8*)(b1 + 2048);
      }

      f32x4 s4[4];
      __builtin_amdgcn_s_setprio(1);
      #pragma unroll
      for (int kt = 0; kt < 4; ++kt) {
        f32x4 a = (f32x4){0.f,0.f,0.f,0.f};
        const int key = kt*16 + r, kgk = key >> 3;
        #pragma unroll
        for (int ks = 0; ks < 2; ++ks) {
          short8 kf8 = *(const short8*)&Ksh[key*64 + ((((qd + ks*4) ^ kgk) & 7) << 3)];
          a = __builtin_amdgcn_mfma_f32_16x16x32_bf16(kf8, qf[ks], a, 0, 0, 0);
        }
        s4[kt] = a;
      }
      __builtin_amdgcn_s_setprio(0);

      const bool diag = (t == qt);
      #pragma unroll
      for (int kt = 0; kt < 4; ++kt)
        #pragma unroll
        for (int rg = 0; rg < 4; ++rg) {
          float v = s4[kt][rg] * 0.125f;
          if (diag && (kt*16 + qd*4 + rg > w*16 + r)) v = -3.0e38f;
          s4[kt][rg] = v;
        }

      float mx = s4[0][0];
      #pragma unroll
      for (int kt = 0; kt < 4; ++kt)
        #pragma unroll
        for (int rg = 0; rg < 4; ++rg) mx = fmaxf(mx, s4[kt][rg]);
      mx = fmaxf(mx, __shfl_xor(mx, 16));
      mx = fmaxf(mx, __shfl_xor(mx, 32));
      const float mn = fmaxf(m_i, mx);
      const float alpha = __expf(m_i - mn);
      m_i = mn;
      l_i *= alpha;

      float lsum = 0.f;
      #pragma unroll
      for (int kt = 0; kt < 4; ++kt) {
        const float p0 = __expf(s4[kt][0] - mn);
        const float p1 = __expf(s4[kt][1] - mn);
        const float p2 = __expf(s4[kt][2] - mn);
        const float p3 = __expf(s4[kt][3] - mn);
        lsum += (p0 + p1) + (p2 + p3);
        uint2 pk;
        pk.x = cvt_pk_bf16(p0, p1);
        pk.y = cvt_pk_bf16(p2, p3);
        *(uint2*)((char*)Pw + r*128 + ((((kt*2 + (qd>>1)) ^ (r&7)) & 7) << 4) + ((qd&1)<<3)) = pk;
      }
      lsum += __shfl_xor(lsum, 16);
      lsum += __shfl_xor(lsum, 32);
      l_i += lsum;
      #pragma unroll
      for (int nt = 0; nt < 4; ++nt)
        #pragma unroll
        for (int rg = 0; rg < 4; ++rg) oacc[nt][rg] *= alpha;

      short8 pf[2];
      #pragma unroll
      for (int ks = 0; ks < 2; ++ks)
        pf[ks] = *(const short8*)&Pw[r*64 + ((((qd + ks*4) ^ (r & 7)) & 7) << 3)];
      __builtin_amdgcn_s_setprio(1);
      #pragma unroll
      for (int nt = 0; nt < 4; ++nt) {
        const int d = nt*16 + r, dg = d >> 3;
        #pragma unroll
        for (int ks = 0; ks < 2; ++ks) {
          short8 vf = *(const short8*)&Vts[d*64 + ((((qd + ks*4) ^ dg) & 7) << 3)];
          oacc[nt] = __builtin_amdgcn_mfma_f32_16x16x32_bf16(vf, pf[ks], oacc[nt], 0, 0, 0);
        }
      }
      __builtin_amdgcn_s_setprio(0);
    }

    const float invl = 1.0f / l_i;
    bfraw* orow = o + (hb + q0 + w*16 + r) * 1024 + h*64;
    #pragma unroll
    for (int nt = 0; nt < 4; ++nt) {
      uint2 ov;
      ov.x = cvt_pk_bf16(oacc[nt][0]*invl, oacc[nt][1]*invl);
      ov.y = cvt_pk_bf16(oacc[nt][2]*invl, oacc[nt][3]*invl);
      *(uint2*)(orow + nt*16 + qd*4) = ov;
    }
  }
}

// ---------------- host ----------------
extern "C" void kernel_launch(void* const* d_in, const int* in_sizes, int n_in,
                              void* d_out, int out_size, void* d_ws, size_t ws_size,
                              hipStream_t stream) {
  (void)in_sizes; (void)n_in;
  const float* x    = (const float*)d_in[0];
  // d_in[1] = causal mask (int32) -- deterministic tril, handled analytically
  const float* ln1g = (const float*)d_in[2];
  const float* ln1b = (const float*)d_in[3];
  const float* ln2g = (const float*)d_in[4];
  const float* ln2b = (const float*)d_in[5];
  const float* qkvw = (const float*)d_in[6];
  const float* outw = (const float*)d_in[7];
  const float* outb = (const float*)d_in[8];
  const float* fc1w = (const float*)d_in[9];
  const float* fc1b = (const float*)d_in[10];
  const float* fc2w = (const float*)d_in[11];
  const float* fc2b = (const float*)d_in[12];
  float* out = (float*)d_out;   // reference output dtype = float32

  char* ws = (char*)d_ws;
  size_t off = 0;
  auto alloc = [&](size_t bytes) -> void* { void* p = ws + off; off += (bytes + 255) & ~(size_t)255; return p; };
  bfraw* wt_qkv = (bfraw*)alloc(3072ULL*1024*2);
  bfraw* wt_out = (bfraw*)alloc(1024ULL*1024*2);
  bfraw* wt_fc1 = (bfraw*)alloc(4096ULL*1024*2);
  bfraw* wt_fc2 = (bfraw*)alloc(1024ULL*4096*2);
  bfraw* hbuf   = (bfraw*)alloc(8192ULL*1024*2);
  float* x1     = (float*)alloc(8192ULL*1024*4);
  char*  big    = (char*) alloc(8192ULL*3072*2 + 8192ULL*1024*2);
  bfraw* qkv  = (bfraw*)big;
  bfraw* obuf = (bfraw*)(big + 8192ULL*3072*2);
  bfraw* hf   = (bfraw*)big;

  if (off > ws_size) {
    (void)hipMemsetAsync(d_out, 0x7F, (size_t)out_size*4, stream);
    return;
  }

  dim3 tb(64, 16);
  transpose_f32_bf16<<<dim3(48, 16), tb, 0, stream>>>(qkvw, wt_qkv, 1024, 3072);
  transpose_f32_bf16<<<dim3(16, 16), tb, 0, stream>>>(outw, wt_out, 1024, 1024);
  transpose_f32_bf16<<<dim3(64, 16), tb, 0, stream>>>(fc1w, wt_fc1, 1024, 4096);
  transpose_f32_bf16<<<dim3(16, 64), tb, 0, stream>>>(fc2w, wt_fc2, 4096, 1024);

  ln_kernel<<<8192, 256, 0, stream>>>(x, ln1g, ln1b, hbuf);
  gemm_bn128<0, bfraw><<<dim3(768), 512, 0, stream>>>(hbuf, wt_qkv, nullptr, nullptr, qkv, 8192, 3072, 1024);
  flash_attn<<<dim3(16, 64), 256, 0, stream>>>(qkv, obuf);
  gemm_bn128<1, float><<<dim3(256), 512, 0, stream>>>(obuf, wt_out, outb, x, x1, 8192, 1024, 1024);
  ln_kernel<<<8192, 256, 0, stream>>>(x1, ln2g, ln2b, hbuf);
  gemm_bn128<2, bfraw><<<dim3(1024), 512, 0, stream>>>(hbuf, wt_fc1, fc1b, nullptr, hf, 8192, 4096, 1024);
  gemm_bn128<1, float><<<dim3(256), 512, 0, stream>>>(hf, wt_fc2, fc2b, x1, out, 8192, 1024, 4096);
}

// Round 5
// 607.175 us; speedup vs baseline: 1.0204x; 1.0158x over previous
//
#include <hip/hip_runtime.h>

typedef unsigned short bfraw;
typedef __attribute__((ext_vector_type(8))) short short8;
typedef __attribute__((ext_vector_type(4))) float f32x4;

__device__ __forceinline__ float b2f(bfraw u){ return __uint_as_float(((unsigned int)u)<<16); }
__device__ __forceinline__ bfraw f2b(float f){
  unsigned int u = __float_as_uint(f);
  return (bfraw)((u + 0x7FFFu + ((u>>16)&1u)) >> 16);
}
__device__ __forceinline__ void store_out(float* p, float v){ *p = v; }
__device__ __forceinline__ void store_out(bfraw* p, float v){ *p = f2b(v); }
__device__ __forceinline__ void gload_lds16(const bfraw* g, short* l) {
  __builtin_amdgcn_global_load_lds((const __attribute__((address_space(1))) void*)g,
                                   (__attribute__((address_space(3))) void*)l, 16, 0, 0);
}
// packs bf16(a) into low 16, bf16(b) into high 16 (RNE) — single VALU op
__device__ __forceinline__ unsigned int cvt_pk_bf16(float a, float b) {
  unsigned int r;
  asm("v_cvt_pk_bf16_f32 %0, %1, %2" : "=v"(r) : "v"(a), "v"(b));
  return r;
}

// ---------------- transpose + convert: out[C][R] = bf16(in[R][C]), in fp32 ------
__global__ __launch_bounds__(1024) void transpose_f32_bf16(const float* __restrict__ in,
                                                           bfraw* __restrict__ out,
                                                           int R, int C) {
  __shared__ bfraw tile[64][65];
  const int tx = threadIdx.x, ty = threadIdx.y;
  const int c0 = blockIdx.x*64, r0 = blockIdx.y*64;
  #pragma unroll
  for (int u = 0; u < 4; ++u)
    tile[ty + u*16][tx] = f2b(in[(size_t)(r0 + ty + u*16)*C + c0 + tx]);
  __syncthreads();
  #pragma unroll
  for (int u = 0; u < 4; ++u)
    out[(size_t)(c0 + ty + u*16)*R + r0 + tx] = tile[tx][ty + u*16];
}

// ---------------- layernorm over D=1024: fp32 in, fp32 params, bf16 out ----------
__global__ __launch_bounds__(256) void ln_kernel(const float* __restrict__ x,
                                                 const float* __restrict__ g,
                                                 const float* __restrict__ b,
                                                 bfraw* __restrict__ out) {
  const int row = blockIdx.x, tid = threadIdx.x;
  const f32x4 v = ((const f32x4*)(x + (size_t)row*1024))[tid];
  float s  = v[0]+v[1]+v[2]+v[3];
  float s2 = v[0]*v[0]+v[1]*v[1]+v[2]*v[2]+v[3]*v[3];
  #pragma unroll
  for (int off = 1; off < 64; off <<= 1) { s += __shfl_xor(s, off); s2 += __shfl_xor(s2, off); }
  __shared__ float red[8];
  const int wv = tid>>6, ln_ = tid&63;
  if (ln_ == 0) { red[wv] = s; red[4+wv] = s2; }
  __syncthreads();
  float a  = red[0]+red[1]+red[2]+red[3];
  float a2 = red[4]+red[5]+red[6]+red[7];
  float mean = a*(1.0f/1024.0f);
  float var  = a2*(1.0f/1024.0f) - mean*mean;
  float inv  = rsqrtf(var + 1e-5f);
  const f32x4 gr = ((const f32x4*)g)[tid];
  const f32x4 br = ((const f32x4*)b)[tid];
  ushort4 o4;
  o4.x = f2b((v[0]-mean)*inv*gr[0] + br[0]);
  o4.y = f2b((v[1]-mean)*inv*gr[1] + br[1]);
  o4.z = f2b((v[2]-mean)*inv*gr[2] + br[2]);
  o4.w = f2b((v[3]-mean)*inv*gr[3] + br[3]);
  ((ushort4*)(out + (size_t)row*1024))[tid] = o4;
}

// ---------------- 256xBN GEMM, BK=64, 8 waves, m201-style 4-phase pipeline -------
// C[M,N] = A[M,K] * Bt[N,K]^T (+epilogue). M%256==0, N%BN==0, K%64==0, grid%8==0.
// BN=256: waves 2Mx4N (wave 128x64); BN=128: waves 4Mx2N (wave 64x64).
// LDS slabs are m-half / n-half major: A slab s holds, for every wave-group wm,
// its rows [wm*(256/WM) + s*RPA , +RPA); B slab s holds rows [wn*64 + s*32, +32).
// Lane-remapped GLOBAL source (gload_lds dest stays linear) realizes this layout
// plus the chunk bank-swizzle ch^=(row&7) (involution on both sides; rule #21).
// Phases per K-tile t (each: reads | stage | barrier | [lgkm0] 16(8) MFMA | barrier):
//   ph0: read af0(A-s0)+bf0(B-s0); stage B-s1(t+1)->obuf ; MFMA q(0,0)
//   ph1: read af1(A-s1)          ; stage A-s0(t+2)->buf  ; MFMA q(1,0)
//   ph2: read bf1(B-s1)          ; stage B-s0(t+2)->buf  ; MFMA q(0,1)
//   ph3: (no reads)              ; stage A-s1(t+2)->buf  ; vmcnt(4+LB); MFMA q(1,1)
// Single counted vmcnt per K-tile; steady state never drains to 0 (T4). All waits
// target loads issued >=3 phases earlier. NO sched_barrier (m141), NO __syncthreads.
// EPI: 0 = none, 1 = +bias +resid, 2 = +bias +exact GELU
template<int BN, int EPI, typename OutT>
__global__ __launch_bounds__(512, 2) void gemm8p(const bfraw* __restrict__ A,
                                                 const bfraw* __restrict__ Bt,
                                                 const float* __restrict__ bias,
                                                 const float* __restrict__ resid,
                                                 OutT* __restrict__ C,
                                                 int M, int N, int K) {
  constexpr int WM  = (BN==256)?2:4;
  constexpr int WN  = 8/WM;
  constexpr int MR  = (256/WM)/16;   // 8 | 4
  constexpr int MRH = MR/2;          // 4 | 2
  constexpr int RPA = 16*MRH;        // 64 | 32
  constexpr int LB  = BN/128;        // 2 | 1
  constexpr int SLABB = BN*32;       // shorts per B slab
  __shared__ __align__(16) short As[2*2*8192];
  __shared__ __align__(16) short Bs[2*2*SLABB];
  const int tid = threadIdx.x;
  const int wv = tid>>6, lane = tid&63;
  const int wm = wv / WN, wn = wv % WN;
  const int q_ = lane>>4, r = lane&15, r7 = r&7;

  // bijective XCD swizzle (all grids are multiples of 8)
  const int nbm = M>>8, nbn = N/BN;
  const int nwg = nbm*nbn;
  int id = (int)blockIdx.x;
  id = (id&7)*(nwg>>3) + (id>>3);
  const int bm = id % nbm, bn = id / nbm;

  // ---- staging geometry: LDS chunk c = l*512+tid -> slab row i=c>>3, ch=c&3..7 ----
  const int i0 = tid>>3;
  const int chs = (tid&7) ^ (i0&7);                 // pre-swizzled source chunk
  unsigned int aoff[2][2], boff[LB][2];
  #pragma unroll
  for (int l = 0; l < 2; ++l)
    #pragma unroll
    for (int s = 0; s < 2; ++s) {
      const int i = l*64 + i0;
      const int g = (i/RPA)*(256/WM) + s*RPA + (i%RPA);
      aoff[l][s] = (unsigned int)(bm*256 + g)*(unsigned int)K + chs*8;
    }
  #pragma unroll
  for (int l = 0; l < LB; ++l)
    #pragma unroll
    for (int s = 0; s < 2; ++s) {
      const int i = l*64 + i0;
      const int g = (i>>5)*64 + s*32 + (i&31);
      boff[l][s] = (unsigned int)(bn*BN + g)*(unsigned int)K + chs*8;
    }
  auto stA = [&](int s, int kb, int b) {
    #pragma unroll
    for (int l = 0; l < 2; ++l)
      gload_lds16(A + aoff[l][s] + kb, As + (b*2+s)*8192 + (l*512+tid)*8);
  };
  auto stB = [&](int s, int kb, int b) {
    #pragma unroll
    for (int l = 0; l < LB; ++l)
      gload_lds16(Bt + boff[l][s] + kb, Bs + (b*2+s)*SLABB + (l*512+tid)*8);
  };

  // ---- fragment read bases (shorts) ----
  const int afb = (wm*RPA + r)*64;
  const int bfb = (wn*32  + r)*64;
  const int csw0 = ((q_     ^ r7) << 3);            // ks=0 swizzled chunk*8
  const int csw1 = (((4+q_) ^ r7) << 3);            // ks=1

  f32x4 acc[MR][4];
  #pragma unroll
  for (int mi = 0; mi < MR; ++mi)
    #pragma unroll
    for (int ni = 0; ni < 4; ++ni)
      acc[mi][ni] = (f32x4){0.f, 0.f, 0.f, 0.f};

  // ---- prologue: tile0 all 4 slabs -> buf0; tile1 A-s0,B-s0,A-s1 -> buf1 ----
  stA(0,0,0); stB(0,0,0); stA(1,0,0); stB(1,0,0);
  stA(0,64,1); stB(0,64,1); stA(1,64,1);
  if constexpr (BN==256) asm volatile("s_waitcnt vmcnt(6)" ::: "memory");
  else                   asm volatile("s_waitcnt vmcnt(5)" ::: "memory");
  __builtin_amdgcn_s_barrier();

  const int nt = K >> 6;
  short8 af0[2][MRH], af1[2][MRH], bf0[2][2], bf1[2][2];
  for (int t = 0; t < nt; ++t) {
    const int buf = t & 1, ob = buf ^ 1;
    const int k1 = (t + 1) << 6, k2 = (t + 2) << 6;
    const bool m1 = (t + 1) < nt, m2 = (t + 2) < nt;

    // ================= ph0: af0 + bf0 ; stage B-s1(t+1) ; MFMA q(0,0) ==========
    {
      const short* Ab = As + (buf*2+0)*8192;
      const short* Bb = Bs + (buf*2+0)*SLABB;
      #pragma unroll
      for (int n = 0; n < 2; ++n) {
        bf0[0][n] = *(const short8*)&Bb[bfb + n*1024 + csw0];
        bf0[1][n] = *(const short8*)&Bb[bfb + n*1024 + csw1];
      }
      #pragma unroll
      for (int m = 0; m < MRH; ++m) {
        af0[0][m] = *(const short8*)&Ab[afb + m*1024 + csw0];
        af0[1][m] = *(const short8*)&Ab[afb + m*1024 + csw1];
      }
    }
    if (m1) stB(1, k1, ob);
    if constexpr (BN==256) asm volatile("s_waitcnt lgkmcnt(8)" ::: "memory");
    __builtin_amdgcn_s_barrier();
    asm volatile("s_waitcnt lgkmcnt(0)" ::: "memory");
    __builtin_amdgcn_s_setprio(1);
    #pragma unroll
    for (int m = 0; m < MRH; ++m)
      #pragma unroll
      for (int n = 0; n < 2; ++n) {
        acc[m][n] = __builtin_amdgcn_mfma_f32_16x16x32_bf16(af0[0][m], bf0[0][n], acc[m][n], 0, 0, 0);
        acc[m][n] = __builtin_amdgcn_mfma_f32_16x16x32_bf16(af0[1][m], bf0[1][n], acc[m][n], 0, 0, 0);
      }
    __builtin_amdgcn_s_setprio(0);
    __builtin_amdgcn_s_barrier();

    // ================= ph1: af1 ; stage A-s0(t+2) ; MFMA q(1,0) ================
    {
      const short* Ab = As + (buf*2+1)*8192;
      #pragma unroll
      for (int m = 0; m < MRH; ++m) {
        af1[0][m] = *(const short8*)&Ab[afb + m*1024 + csw0];
        af1[1][m] = *(const short8*)&Ab[afb + m*1024 + csw1];
      }
    }
    if (m2) stA(0, k2, buf);
    __builtin_amdgcn_s_barrier();
    asm volatile("s_waitcnt lgkmcnt(0)" ::: "memory");
    __builtin_amdgcn_s_setprio(1);
    #pragma unroll
    for (int m = 0; m < MRH; ++m)
      #pragma unroll
      for (int n = 0; n < 2; ++n) {
        acc[MRH+m][n] = __builtin_amdgcn_mfma_f32_16x16x32_bf16(af1[0][m], bf0[0][n], acc[MRH+m][n], 0, 0, 0);
        acc[MRH+m][n] = __builtin_amdgcn_mfma_f32_16x16x32_bf16(af1[1][m], bf0[1][n], acc[MRH+m][n], 0, 0, 0);
      }
    __builtin_amdgcn_s_setprio(0);
    __builtin_amdgcn_s_barrier();

    // ================= ph2: bf1 ; stage B-s0(t+2) ; MFMA q(0,1) ================
    {
      const short* Bb = Bs + (buf*2+1)*SLABB;
      #pragma unroll
      for (int n = 0; n < 2; ++n) {
        bf1[0][n] = *(const short8*)&Bb[bfb + n*1024 + csw0];
        bf1[1][n] = *(const short8*)&Bb[bfb + n*1024 + csw1];
      }
    }
    if (m2) stB(0, k2, buf);
    __builtin_amdgcn_s_barrier();
    asm volatile("s_waitcnt lgkmcnt(0)" ::: "memory");
    __builtin_amdgcn_s_setprio(1);
    #pragma unroll
    for (int m = 0; m < MRH; ++m)
      #pragma unroll
      for (int n = 0; n < 2; ++n) {
        acc[m][2+n] = __builtin_amdgcn_mfma_f32_16x16x32_bf16(af0[0][m], bf1[0][n], acc[m][2+n], 0, 0, 0);
        acc[m][2+n] = __builtin_amdgcn_mfma_f32_16x16x32_bf16(af0[1][m], bf1[1][n], acc[m][2+n], 0, 0, 0);
      }
    __builtin_amdgcn_s_setprio(0);
    __builtin_amdgcn_s_barrier();

    // ================= ph3: stage A-s1(t+2) ; counted vmcnt ; MFMA q(1,1) ======
    if (m2) stA(1, k2, buf);
    if (m2) {
      if constexpr (BN==256) asm volatile("s_waitcnt vmcnt(6)" ::: "memory");
      else                   asm volatile("s_waitcnt vmcnt(5)" ::: "memory");
    } else if (m1) {
      asm volatile("s_waitcnt vmcnt(0)" ::: "memory");
    }
    __builtin_amdgcn_s_barrier();
    __builtin_amdgcn_s_setprio(1);
    #pragma unroll
    for (int m = 0; m < MRH; ++m)
      #pragma unroll
      for (int n = 0; n < 2; ++n) {
        acc[MRH+m][2+n] = __builtin_amdgcn_mfma_f32_16x16x32_bf16(af1[0][m], bf1[0][n], acc[MRH+m][2+n], 0, 0, 0);
        acc[MRH+m][2+n] = __builtin_amdgcn_mfma_f32_16x16x32_bf16(af1[1][m], bf1[1][n], acc[MRH+m][2+n], 0, 0, 0);
      }
    __builtin_amdgcn_s_setprio(0);
    __builtin_amdgcn_s_barrier();
  }

  // ---- epilogue (register-only inputs; no LDS) ----
  #pragma unroll
  for (int mi = 0; mi < MR; ++mi) {
    #pragma unroll
    for (int ni = 0; ni < 4; ++ni) {
      const int gcol = bn*BN + wn*64 + ni*16 + r;
      float bv = 0.f;
      if constexpr (EPI != 0) bv = bias[gcol];
      #pragma unroll
      for (int rg = 0; rg < 4; ++rg) {
        const int grow = bm*256 + wm*(MR*16) + mi*16 + q_*4 + rg;
        float val = acc[mi][ni][rg];
        if constexpr (EPI != 0) val += bv;
        if constexpr (EPI == 2) val = 0.5f*val*(1.0f + erff(val*0.70710678118654752f));
        if constexpr (EPI == 1) val += resid[(size_t)grow*N + gcol];
        store_out(&C[(size_t)grow*N + gcol], val);
      }
    }
  }
}

// ---------------- MFMA flash attention (causal), T=2048, HD=64, scale=1/8 ---------
// (unchanged: S^T orientation, scalar softmax state, cvt_pk P-pack)
__global__ __launch_bounds__(256) void flash_attn(const bfraw* __restrict__ qkv,
                                                  bfraw* __restrict__ o) {
  __shared__ __align__(16) short Ksh[4096];
  __shared__ __align__(16) short Vts[4096];
  __shared__ __align__(16) short Psh[4096];
  const int tid = threadIdx.x;
  const int w = tid >> 6, lane = tid & 63;
  const int r = lane & 15, qd = lane >> 4;
  const int bb = blockIdx.y >> 4, h = blockIdx.y & 15;
  const size_t hb = (size_t)bb * 2048;
  short* Pw = &Psh[w * 1024];
  const int f0 = tid, f1 = tid + 256;
  const int key0 = f0 >> 3, dc0 = (f0 & 7) * 8;
  const int key1 = f1 >> 3, dc1 = (f1 & 7) * 8;

  for (int pass = 0; pass < 2; ++pass) {
    const int qt = pass ? (31 - (int)blockIdx.x) : (int)blockIdx.x;
    const int q0 = qt * 64;
    const int ntile = qt + 1;

    short8 qf[2];
    {
      const bfraw* qrow = qkv + (hb + q0 + w*16 + r) * 3072 + h*64;
      qf[0] = *(const short8*)(qrow + qd*8);
      qf[1] = *(const short8*)(qrow + qd*8 + 32);
    }

    f32x4 oacc[4];
    #pragma unroll
    for (int nt = 0; nt < 4; ++nt) oacc[nt] = (f32x4){0.f,0.f,0.f,0.f};
    float m_i = -3.0e38f;
    float l_i = 0.f;

    short8 kpre[2], vpre[2];
    {
      const bfraw* b0 = qkv + (hb + key0) * 3072 + h*64 + dc0;
      const bfraw* b1 = qkv + (hb + key1) * 3072 + h*64 + dc1;
      kpre[0] = *(const short8*)(b0 + 1024); vpre[0] = *(const short8*)(b0 + 2048);
      kpre[1] = *(const short8*)(b1 + 1024); vpre[1] = *(const short8*)(b1 + 2048);
    }

    for (int t = 0; t < ntile; ++t) {
      __syncthreads();
      #pragma unroll
      for (int pz = 0; pz < 2; ++pz) {
        const int key = pz ? key1 : key0, dc = pz ? dc1 : dc0;
        *(short8*)&Ksh[key*64 + ((((dc>>3) ^ (key>>3)) & 7) << 3)] = kpre[pz];
        const int kg = key >> 3, k7 = key & 7, dg = dc >> 3;
        #pragma unroll
        for (int i2 = 0; i2 < 8; ++i2)
          Vts[(dc + i2)*64 + (((kg ^ dg) & 7) << 3) + k7] = vpre[pz][i2];
      }
      __syncthreads();
      if (t + 1 < ntile) {
        const int j0n = (t + 1) * 64;
        const bfraw* b0 = qkv + (hb + j0n + key0) * 3072 + h*64 + dc0;
        const bfraw* b1 = qkv + (hb + j0n + key1) * 3072 + h*64 + dc1;
        kpre[0] = *(const short8*)(b0 + 1024); vpre[0] = *(const short8*)(b0 + 2048);
        kpre[1] = *(const short8*)(b1 + 1024); vpre[1] = *(const short8*)(b1 + 2048);
      }

      f32x4 s4[4];
      __builtin_amdgcn_s_setprio(1);
      #pragma unroll
      for (int kt = 0; kt < 4; ++kt) {
        f32x4 a = (f32x4){0.f,0.f,0.f,0.f};
        const int key = kt*16 + r, kgk = key >> 3;
        #pragma unroll
        for (int ks = 0; ks < 2; ++ks) {
          short8 kf8 = *(const short8*)&Ksh[key*64 + ((((qd + ks*4) ^ kgk) & 7) << 3)];
          a = __builtin_amdgcn_mfma_f32_16x16x32_bf16(kf8, qf[ks], a, 0, 0, 0);
        }
        s4[kt] = a;
      }
      __builtin_amdgcn_s_setprio(0);

      const bool diag = (t == qt);
      #pragma unroll
      for (int kt = 0; kt < 4; ++kt)
        #pragma unroll
        for (int rg = 0; rg < 4; ++rg) {
          float v = s4[kt][rg] * 0.125f;
          if (diag && (kt*16 + qd*4 + rg > w*16 + r)) v = -3.0e38f;
          s4[kt][rg] = v;
        }

      float mx = s4[0][0];
      #pragma unroll
      for (int kt = 0; kt < 4; ++kt)
        #pragma unroll
        for (int rg = 0; rg < 4; ++rg) mx = fmaxf(mx, s4[kt][rg]);
      mx = fmaxf(mx, __shfl_xor(mx, 16));
      mx = fmaxf(mx, __shfl_xor(mx, 32));
      const float mn = fmaxf(m_i, mx);
      const float alpha = __expf(m_i - mn);
      m_i = mn;
      l_i *= alpha;

      float lsum = 0.f;
      #pragma unroll
      for (int kt = 0; kt < 4; ++kt) {
        const float p0 = __expf(s4[kt][0] - mn);
        const float p1 = __expf(s4[kt][1] - mn);
        const float p2 = __expf(s4[kt][2] - mn);
        const float p3 = __expf(s4[kt][3] - mn);
        lsum += (p0 + p1) + (p2 + p3);
        uint2 pk;
        pk.x = cvt_pk_bf16(p0, p1);
        pk.y = cvt_pk_bf16(p2, p3);
        *(uint2*)((char*)Pw + r*128 + ((((kt*2 + (qd>>1)) ^ (r&7)) & 7) << 4) + ((qd&1)<<3)) = pk;
      }
      lsum += __shfl_xor(lsum, 16);
      lsum += __shfl_xor(lsum, 32);
      l_i += lsum;
      #pragma unroll
      for (int nt = 0; nt < 4; ++nt)
        #pragma unroll
        for (int rg = 0; rg < 4; ++rg) oacc[nt][rg] *= alpha;

      short8 pf[2];
      #pragma unroll
      for (int ks = 0; ks < 2; ++ks)
        pf[ks] = *(const short8*)&Pw[r*64 + ((((qd + ks*4) ^ (r & 7)) & 7) << 3)];
      __builtin_amdgcn_s_setprio(1);
      #pragma unroll
      for (int nt = 0; nt < 4; ++nt) {
        const int d = nt*16 + r, dg = d >> 3;
        #pragma unroll
        for (int ks = 0; ks < 2; ++ks) {
          short8 vf = *(const short8*)&Vts[d*64 + ((((qd + ks*4) ^ dg) & 7) << 3)];
          oacc[nt] = __builtin_amdgcn_mfma_f32_16x16x32_bf16(vf, pf[ks], oacc[nt], 0, 0, 0);
        }
      }
      __builtin_amdgcn_s_setprio(0);
    }

    const float invl = 1.0f / l_i;
    bfraw* orow = o + (hb + q0 + w*16 + r) * 1024 + h*64;
    #pragma unroll
    for (int nt = 0; nt < 4; ++nt) {
      uint2 ov;
      ov.x = cvt_pk_bf16(oacc[nt][0]*invl, oacc[nt][1]*invl);
      ov.y = cvt_pk_bf16(oacc[nt][2]*invl, oacc[nt][3]*invl);
      *(uint2*)(orow + nt*16 + qd*4) = ov;
    }
  }
}

// ---------------- host ----------------
extern "C" void kernel_launch(void* const* d_in, const int* in_sizes, int n_in,
                              void* d_out, int out_size, void* d_ws, size_t ws_size,
                              hipStream_t stream) {
  (void)in_sizes; (void)n_in;
  const float* x    = (const float*)d_in[0];
  // d_in[1] = causal mask (int32) -- deterministic tril, handled analytically
  const float* ln1g = (const float*)d_in[2];
  const float* ln1b = (const float*)d_in[3];
  const float* ln2g = (const float*)d_in[4];
  const float* ln2b = (const float*)d_in[5];
  const float* qkvw = (const float*)d_in[6];
  const float* outw = (const float*)d_in[7];
  const float* outb = (const float*)d_in[8];
  const float* fc1w = (const float*)d_in[9];
  const float* fc1b = (const float*)d_in[10];
  const float* fc2w = (const float*)d_in[11];
  const float* fc2b = (const float*)d_in[12];
  float* out = (float*)d_out;   // reference output dtype = float32

  char* ws = (char*)d_ws;
  size_t off = 0;
  auto alloc = [&](size_t bytes) -> void* { void* p = ws + off; off += (bytes + 255) & ~(size_t)255; return p; };
  bfraw* wt_qkv = (bfraw*)alloc(3072ULL*1024*2);
  bfraw* wt_out = (bfraw*)alloc(1024ULL*1024*2);
  bfraw* wt_fc1 = (bfraw*)alloc(4096ULL*1024*2);
  bfraw* wt_fc2 = (bfraw*)alloc(1024ULL*4096*2);
  bfraw* hbuf   = (bfraw*)alloc(8192ULL*1024*2);
  float* x1     = (float*)alloc(8192ULL*1024*4);
  char*  big    = (char*) alloc(8192ULL*3072*2 + 8192ULL*1024*2);
  bfraw* qkv  = (bfraw*)big;
  bfraw* obuf = (bfraw*)(big + 8192ULL*3072*2);
  bfraw* hf   = (bfraw*)big;

  if (off > ws_size) {
    (void)hipMemsetAsync(d_out, 0x7F, (size_t)out_size*4, stream);
    return;
  }

  dim3 tb(64, 16);
  transpose_f32_bf16<<<dim3(48, 16), tb, 0, stream>>>(qkvw, wt_qkv, 1024, 3072);
  transpose_f32_bf16<<<dim3(16, 16), tb, 0, stream>>>(outw, wt_out, 1024, 1024);
  transpose_f32_bf16<<<dim3(64, 16), tb, 0, stream>>>(fc1w, wt_fc1, 1024, 4096);
  transpose_f32_bf16<<<dim3(16, 64), tb, 0, stream>>>(fc2w, wt_fc2, 4096, 1024);

  ln_kernel<<<8192, 256, 0, stream>>>(x, ln1g, ln1b, hbuf);
  // qkv: M=8192 N=3072 K=1024 -> BN=128 grid 768 (3 exact CU rounds)
  gemm8p<128, 0, bfraw><<<dim3(768), 512, 0, stream>>>(hbuf, wt_qkv, nullptr, nullptr, qkv, 8192, 3072, 1024);
  flash_attn<<<dim3(16, 64), 256, 0, stream>>>(qkv, obuf);
  // out: M=8192 N=1024 K=1024 -> BN=128 grid 256 (exact)
  gemm8p<128, 1, float><<<dim3(256), 512, 0, stream>>>(obuf, wt_out, outb, x, x1, 8192, 1024, 1024);
  ln_kernel<<<8192, 256, 0, stream>>>(x1, ln2g, ln2b, hbuf);
  // fc1: M=8192 N=4096 K=1024 -> BN=256 grid 512 (2 exact rounds)
  gemm8p<256, 2, bfraw><<<dim3(512), 512, 0, stream>>>(hbuf, wt_fc1, fc1b, nullptr, hf, 8192, 4096, 1024);
  // fc2: M=8192 N=1024 K=4096 -> BN=128 grid 256 (exact)
  gemm8p<128, 1, float><<<dim3(256), 512, 0, stream>>>(hf, wt_fc2, fc2b, x1, out, 8192, 1024, 4096);
}

// Round 6
// 598.966 us; speedup vs baseline: 1.0344x; 1.0137x over previous
//
#include <hip/hip_runtime.h>

typedef unsigned short bfraw;
typedef __attribute__((ext_vector_type(8))) short short8;
typedef __attribute__((ext_vector_type(4))) float f32x4;

__device__ __forceinline__ float b2f(bfraw u){ return __uint_as_float(((unsigned int)u)<<16); }
__device__ __forceinline__ bfraw f2b(float f){
  unsigned int u = __float_as_uint(f);
  return (bfraw)((u + 0x7FFFu + ((u>>16)&1u)) >> 16);
}
__device__ __forceinline__ void store_out(float* p, float v){ *p = v; }
__device__ __forceinline__ void store_out(bfraw* p, float v){ *p = f2b(v); }
__device__ __forceinline__ void gload_lds16(const bfraw* g, short* l) {
  __builtin_amdgcn_global_load_lds((const __attribute__((address_space(1))) void*)g,
                                   (__attribute__((address_space(3))) void*)l, 16, 0, 0);
}
// packs bf16(a) into low 16, bf16(b) into high 16 (RNE) — single VALU op
__device__ __forceinline__ unsigned int cvt_pk_bf16(float a, float b) {
  unsigned int r;
  asm("v_cvt_pk_bf16_f32 %0, %1, %2" : "=v"(r) : "v"(a), "v"(b));
  return r;
}

// ---------------- transpose + convert: out[C][R] = bf16(in[R][C]), in fp32 ------
__global__ __launch_bounds__(1024) void transpose_f32_bf16(const float* __restrict__ in,
                                                           bfraw* __restrict__ out,
                                                           int R, int C) {
  __shared__ bfraw tile[64][65];
  const int tx = threadIdx.x, ty = threadIdx.y;
  const int c0 = blockIdx.x*64, r0 = blockIdx.y*64;
  #pragma unroll
  for (int u = 0; u < 4; ++u)
    tile[ty + u*16][tx] = f2b(in[(size_t)(r0 + ty + u*16)*C + c0 + tx]);
  __syncthreads();
  #pragma unroll
  for (int u = 0; u < 4; ++u)
    out[(size_t)(c0 + ty + u*16)*R + r0 + tx] = tile[tx][ty + u*16];
}

// ---------------- layernorm over D=1024: fp32 in, fp32 params, bf16 out ----------
__global__ __launch_bounds__(256) void ln_kernel(const float* __restrict__ x,
                                                 const float* __restrict__ g,
                                                 const float* __restrict__ b,
                                                 bfraw* __restrict__ out) {
  const int row = blockIdx.x, tid = threadIdx.x;
  const f32x4 v = ((const f32x4*)(x + (size_t)row*1024))[tid];
  float s  = v[0]+v[1]+v[2]+v[3];
  float s2 = v[0]*v[0]+v[1]*v[1]+v[2]*v[2]+v[3]*v[3];
  #pragma unroll
  for (int off = 1; off < 64; off <<= 1) { s += __shfl_xor(s, off); s2 += __shfl_xor(s2, off); }
  __shared__ float red[8];
  const int wv = tid>>6, ln_ = tid&63;
  if (ln_ == 0) { red[wv] = s; red[4+wv] = s2; }
  __syncthreads();
  float a  = red[0]+red[1]+red[2]+red[3];
  float a2 = red[4]+red[5]+red[6]+red[7];
  float mean = a*(1.0f/1024.0f);
  float var  = a2*(1.0f/1024.0f) - mean*mean;
  float inv  = rsqrtf(var + 1e-5f);
  const f32x4 gr = ((const f32x4*)g)[tid];
  const f32x4 br = ((const f32x4*)b)[tid];
  ushort4 o4;
  o4.x = f2b((v[0]-mean)*inv*gr[0] + br[0]);
  o4.y = f2b((v[1]-mean)*inv*gr[1] + br[1]);
  o4.z = f2b((v[2]-mean)*inv*gr[2] + br[2]);
  o4.w = f2b((v[3]-mean)*inv*gr[3] + br[3]);
  ((ushort4*)(out + (size_t)row*1024))[tid] = o4;
}

// ---------------- GEMM: C[M,N] = A[M,K] * Bt[N,K]^T (+epilogue) -------------------
// R1-proven m97 structure (128^2 tile, 32KB LDS, ~3 blocks/CU cross-block overlap).
// New: 1D grid + bijective XCD swizzle with bn-fast ordering inside each XCD chunk
// -> each XCD's resident blocks share a small bm range (A panels ~2MB fit 4MB L2);
// B (small) is L3-shared. nwg % 8 == 0 for all launches here.
// EPI: 0 = none, 1 = +bias +resid, 2 = +bias +exact GELU
template<int EPI, typename OutT>
__global__ __launch_bounds__(256) void gemm_bt(const bfraw* __restrict__ A,
                                               const bfraw* __restrict__ Bt,
                                               const float* __restrict__ bias,
                                               const float* __restrict__ resid,
                                               OutT* __restrict__ C,
                                               int M, int N, int K) {
  __shared__ __align__(16) short As[128*32];
  __shared__ __align__(16) short Bs[128*32];
  const int tid = threadIdx.x;
  const int wave = tid>>6, lane = tid&63;
  const int wm = wave>>1, wn = wave&1;
  const int q = lane>>4, r = lane&15;
  // bijective XCD swizzle, bn-fast within chunk (A-panel reuse in per-XCD L2)
  const int nbm = M>>7, nbn = N>>7, nwg = nbm*nbn;
  int id = (int)blockIdx.x;
  id = (id&7)*(nwg>>3) + (id>>3);
  const int bm = id / nbn, bn = id % nbn;

  // staging: tile 128 rows x 32 bf16 = 512 x 16B chunks; thread covers f=tid, f=256+tid.
  const int m0 = tid>>2, c0 = tid&3;
  const bfraw* Ag0 = A  + (size_t)(bm*128      + m0)*K + c0*8;
  const bfraw* Ag1 = A  + (size_t)(bm*128 + 64 + m0)*K + c0*8;
  const bfraw* Bg0 = Bt + (size_t)(bn*128      + m0)*K + c0*8;
  const bfraw* Bg1 = Bt + (size_t)(bn*128 + 64 + m0)*K + c0*8;
  short* Al0 = &As[tid*8];
  short* Al1 = &As[(256+tid)*8];
  short* Bl0 = &Bs[tid*8];
  short* Bl1 = &Bs[(256+tid)*8];

  f32x4 acc[4][4];
  #pragma unroll
  for (int mi = 0; mi < 4; ++mi)
    #pragma unroll
    for (int ni = 0; ni < 4; ++ni)
      acc[mi][ni] = (f32x4){0.f, 0.f, 0.f, 0.f};

  for (int k0 = 0; k0 < K; k0 += 32) {
    __syncthreads();               // protect LDS readers of previous tile
    gload_lds16(Ag0 + k0, Al0);
    gload_lds16(Ag1 + k0, Al1);
    gload_lds16(Bg0 + k0, Bl0);
    gload_lds16(Bg1 + k0, Bl1);
    __syncthreads();               // vmcnt drained by compiler before barrier
    short8 af[4], bfr[4];
    #pragma unroll
    for (int mi = 0; mi < 4; ++mi)
      af[mi] = *(const short8*)&As[(wm*64 + mi*16 + r)*32 + q*8];
    #pragma unroll
    for (int ni = 0; ni < 4; ++ni)
      bfr[ni] = *(const short8*)&Bs[(wn*64 + ni*16 + r)*32 + q*8];
    #pragma unroll
    for (int mi = 0; mi < 4; ++mi)
      #pragma unroll
      for (int ni = 0; ni < 4; ++ni)
        acc[mi][ni] = __builtin_amdgcn_mfma_f32_16x16x32_bf16(af[mi], bfr[ni], acc[mi][ni], 0, 0, 0);
  }

  #pragma unroll
  for (int mi = 0; mi < 4; ++mi) {
    #pragma unroll
    for (int ni = 0; ni < 4; ++ni) {
      const int gcol = bn*128 + wn*64 + ni*16 + r;
      float bv = 0.f;
      if constexpr (EPI != 0) bv = bias[gcol];
      #pragma unroll
      for (int rg = 0; rg < 4; ++rg) {
        const int grow = bm*128 + wm*64 + mi*16 + q*4 + rg;
        float val = acc[mi][ni][rg];
        if constexpr (EPI != 0) val += bv;
        if constexpr (EPI == 2) val = 0.5f*val*(1.0f + erff(val*0.70710678118654752f));
        if constexpr (EPI == 1) val += resid[(size_t)grow*N + gcol];
        store_out(&C[(size_t)grow*N + gcol], val);
      }
    }
  }
}

// ---------------- MFMA flash attention (causal), T=2048, HD=64, scale=1/8 ---------
// v3: LDS row stride 64 -> 72 shorts (144B). A 128B row stride put every row at
// bank phase 0, so row-varying ds_read_b128 (K-reads, V-reads, P-reads: 16 rows,
// fixed chunk) hit 8 lanes per 4-bank column = 8-way conflicts (the measured
// 2.8e7 SQ_LDS_BANK_CONFLICT). 144B rotates bank phase by 4/row -> 2-way (free).
// XOR chunk swizzles unchanged (write-side bank math unaffected: 8*144B % 128B == 0).
__global__ __launch_bounds__(256) void flash_attn(const bfraw* __restrict__ qkv,
                                                  bfraw* __restrict__ o) {
  __shared__ __align__(16) short Ksh[64*72];
  __shared__ __align__(16) short Vts[64*72];
  __shared__ __align__(16) short Psh[4*16*72];
  const int tid = threadIdx.x;
  const int w = tid >> 6, lane = tid & 63;
  const int r = lane & 15, qd = lane >> 4;
  const int bb = blockIdx.y >> 4, h = blockIdx.y & 15;
  const size_t hb = (size_t)bb * 2048;
  short* Pw = &Psh[w * 1152];
  const int f0 = tid, f1 = tid + 256;
  const int key0 = f0 >> 3, dc0 = (f0 & 7) * 8;
  const int key1 = f1 >> 3, dc1 = (f1 & 7) * 8;

  for (int pass = 0; pass < 2; ++pass) {
    const int qt = pass ? (31 - (int)blockIdx.x) : (int)blockIdx.x;
    const int q0 = qt * 64;
    const int ntile = qt + 1;

    // Q fragments: lane holds Q[q=r][k=qd*8+ks*32+j] (B operand)
    short8 qf[2];
    {
      const bfraw* qrow = qkv + (hb + q0 + w*16 + r) * 3072 + h*64;
      qf[0] = *(const short8*)(qrow + qd*8);
      qf[1] = *(const short8*)(qrow + qd*8 + 32);
    }

    f32x4 oacc[4];
    #pragma unroll
    for (int nt = 0; nt < 4; ++nt) oacc[nt] = (f32x4){0.f,0.f,0.f,0.f};
    float m_i = -3.0e38f;
    float l_i = 0.f;

    short8 kpre[2], vpre[2];
    {
      const bfraw* b0 = qkv + (hb + key0) * 3072 + h*64 + dc0;
      const bfraw* b1 = qkv + (hb + key1) * 3072 + h*64 + dc1;
      kpre[0] = *(const short8*)(b0 + 1024); vpre[0] = *(const short8*)(b0 + 2048);
      kpre[1] = *(const short8*)(b1 + 1024); vpre[1] = *(const short8*)(b1 + 2048);
    }

    for (int t = 0; t < ntile; ++t) {
      __syncthreads();   // protect LDS vs previous tile / previous pass
      // ---- write prefetched K [key][dim] and Vt [dim][key] (swizzled, stride 72) --
      #pragma unroll
      for (int pz = 0; pz < 2; ++pz) {
        const int key = pz ? key1 : key0, dc = pz ? dc1 : dc0;
        *(short8*)&Ksh[key*72 + ((((dc>>3) ^ (key>>3)) & 7) << 3)] = kpre[pz];
        const int kg = key >> 3, k7 = key & 7, dg = dc >> 3;
        #pragma unroll
        for (int i2 = 0; i2 < 8; ++i2)
          Vts[(dc + i2)*72 + (((kg ^ dg) & 7) << 3) + k7] = vpre[pz][i2];
      }
      __syncthreads();
      // ---- prefetch next tile into regs (overlaps compute below) ----
      if (t + 1 < ntile) {
        const int j0n = (t + 1) * 64;
        const bfraw* b0 = qkv + (hb + j0n + key0) * 3072 + h*64 + dc0;
        const bfraw* b1 = qkv + (hb + j0n + key1) * 3072 + h*64 + dc1;
        kpre[0] = *(const short8*)(b0 + 1024); vpre[0] = *(const short8*)(b0 + 2048);
        kpre[1] = *(const short8*)(b1 + 1024); vpre[1] = *(const short8*)(b1 + 2048);
      }

      // ---- S^T = K Q^T : col = lane&15 = q-row, row = kt*16 + qd*4 + rg = key ----
      f32x4 s4[4];
      __builtin_amdgcn_s_setprio(1);
      #pragma unroll
      for (int kt = 0; kt < 4; ++kt) {
        f32x4 a = (f32x4){0.f,0.f,0.f,0.f};
        const int key = kt*16 + r, kgk = key >> 3;
        #pragma unroll
        for (int ks = 0; ks < 2; ++ks) {
          short8 kf8 = *(const short8*)&Ksh[key*72 + ((((qd + ks*4) ^ kgk) & 7) << 3)];
          a = __builtin_amdgcn_mfma_f32_16x16x32_bf16(kf8, qf[ks], a, 0, 0, 0);
        }
        s4[kt] = a;
      }
      __builtin_amdgcn_s_setprio(0);

      // ---- scale + causal mask (diagonal tile only) ----
      const bool diag = (t == qt);
      #pragma unroll
      for (int kt = 0; kt < 4; ++kt)
        #pragma unroll
        for (int rg = 0; rg < 4; ++rg) {
          float v = s4[kt][rg] * 0.125f;
          if (diag && (kt*16 + qd*4 + rg > w*16 + r)) v = -3.0e38f;
          s4[kt][rg] = v;
        }

      // ---- online softmax: lane owns row r; 16 keys + xor(16,32) reduce ----
      float mx = s4[0][0];
      #pragma unroll
      for (int kt = 0; kt < 4; ++kt)
        #pragma unroll
        for (int rg = 0; rg < 4; ++rg) mx = fmaxf(mx, s4[kt][rg]);
      mx = fmaxf(mx, __shfl_xor(mx, 16));
      mx = fmaxf(mx, __shfl_xor(mx, 32));
      const float mn = fmaxf(m_i, mx);
      const float alpha = __expf(m_i - mn);
      m_i = mn;
      l_i *= alpha;

      // P = exp(s - m): pack 4 consecutive keys -> one 8B swizzled store per kt
      float lsum = 0.f;
      #pragma unroll
      for (int kt = 0; kt < 4; ++kt) {
        const float p0 = __expf(s4[kt][0] - mn);
        const float p1 = __expf(s4[kt][1] - mn);
        const float p2 = __expf(s4[kt][2] - mn);
        const float p3 = __expf(s4[kt][3] - mn);
        lsum += (p0 + p1) + (p2 + p3);
        uint2 pk;
        pk.x = cvt_pk_bf16(p0, p1);
        pk.y = cvt_pk_bf16(p2, p3);
        *(uint2*)((char*)Pw + r*144 + ((((kt*2 + (qd>>1)) ^ (r&7)) & 7) << 4) + ((qd&1)<<3)) = pk;
      }
      lsum += __shfl_xor(lsum, 16);
      lsum += __shfl_xor(lsum, 32);
      l_i += lsum;
      #pragma unroll
      for (int nt = 0; nt < 4; ++nt)
        #pragma unroll
        for (int rg = 0; rg < 4; ++rg) oacc[nt][rg] *= alpha;

      // ---- O^T += Vt Pt ----
      short8 pf[2];
      #pragma unroll
      for (int ks = 0; ks < 2; ++ks)
        pf[ks] = *(const short8*)&Pw[r*72 + ((((qd + ks*4) ^ (r & 7)) & 7) << 3)];
      __builtin_amdgcn_s_setprio(1);
      #pragma unroll
      for (int nt = 0; nt < 4; ++nt) {
        const int d = nt*16 + r, dg = d >> 3;
        #pragma unroll
        for (int ks = 0; ks < 2; ++ks) {
          short8 vf = *(const short8*)&Vts[d*72 + ((((qd + ks*4) ^ dg) & 7) << 3)];
          oacc[nt] = __builtin_amdgcn_mfma_f32_16x16x32_bf16(vf, pf[ks], oacc[nt], 0, 0, 0);
        }
      }
      __builtin_amdgcn_s_setprio(0);
    }

    // epilogue: O[q=r][d = nt*16 + qd*4 + rg], lane-local scale, 8B vector stores
    const float invl = 1.0f / l_i;
    bfraw* orow = o + (hb + q0 + w*16 + r) * 1024 + h*64;
    #pragma unroll
    for (int nt = 0; nt < 4; ++nt) {
      uint2 ov;
      ov.x = cvt_pk_bf16(oacc[nt][0]*invl, oacc[nt][1]*invl);
      ov.y = cvt_pk_bf16(oacc[nt][2]*invl, oacc[nt][3]*invl);
      *(uint2*)(orow + nt*16 + qd*4) = ov;
    }
  }
}

// ---------------- host ----------------
extern "C" void kernel_launch(void* const* d_in, const int* in_sizes, int n_in,
                              void* d_out, int out_size, void* d_ws, size_t ws_size,
                              hipStream_t stream) {
  (void)in_sizes; (void)n_in;
  const float* x    = (const float*)d_in[0];
  // d_in[1] = causal mask (int32) -- deterministic tril, handled analytically
  const float* ln1g = (const float*)d_in[2];
  const float* ln1b = (const float*)d_in[3];
  const float* ln2g = (const float*)d_in[4];
  const float* ln2b = (const float*)d_in[5];
  const float* qkvw = (const float*)d_in[6];
  const float* outw = (const float*)d_in[7];
  const float* outb = (const float*)d_in[8];
  const float* fc1w = (const float*)d_in[9];
  const float* fc1b = (const float*)d_in[10];
  const float* fc2w = (const float*)d_in[11];
  const float* fc2b = (const float*)d_in[12];
  float* out = (float*)d_out;   // reference output dtype = float32

  char* ws = (char*)d_ws;
  size_t off = 0;
  auto alloc = [&](size_t bytes) -> void* { void* p = ws + off; off += (bytes + 255) & ~(size_t)255; return p; };
  bfraw* wt_qkv = (bfraw*)alloc(3072ULL*1024*2);
  bfraw* wt_out = (bfraw*)alloc(1024ULL*1024*2);
  bfraw* wt_fc1 = (bfraw*)alloc(4096ULL*1024*2);
  bfraw* wt_fc2 = (bfraw*)alloc(1024ULL*4096*2);
  bfraw* hbuf   = (bfraw*)alloc(8192ULL*1024*2);
  float* x1     = (float*)alloc(8192ULL*1024*4);
  char*  big    = (char*) alloc(8192ULL*3072*2 + 8192ULL*1024*2);
  bfraw* qkv  = (bfraw*)big;
  bfraw* obuf = (bfraw*)(big + 8192ULL*3072*2);
  bfraw* hf   = (bfraw*)big;

  if (off > ws_size) {
    (void)hipMemsetAsync(d_out, 0x7F, (size_t)out_size*4, stream);
    return;
  }

  dim3 tb(64, 16);
  transpose_f32_bf16<<<dim3(48, 16), tb, 0, stream>>>(qkvw, wt_qkv, 1024, 3072);
  transpose_f32_bf16<<<dim3(16, 16), tb, 0, stream>>>(outw, wt_out, 1024, 1024);
  transpose_f32_bf16<<<dim3(64, 16), tb, 0, stream>>>(fc1w, wt_fc1, 1024, 4096);
  transpose_f32_bf16<<<dim3(16, 64), tb, 0, stream>>>(fc2w, wt_fc2, 4096, 1024);

  ln_kernel<<<8192, 256, 0, stream>>>(x, ln1g, ln1b, hbuf);
  gemm_bt<0, bfraw><<<dim3(1536), 256, 0, stream>>>(hbuf, wt_qkv, nullptr, nullptr, qkv, 8192, 3072, 1024);
  flash_attn<<<dim3(16, 64), 256, 0, stream>>>(qkv, obuf);
  gemm_bt<1, float><<<dim3(512), 256, 0, stream>>>(obuf, wt_out, outb, x, x1, 8192, 1024, 1024);
  ln_kernel<<<8192, 256, 0, stream>>>(x1, ln2g, ln2b, hbuf);
  gemm_bt<2, bfraw><<<dim3(2048), 256, 0, stream>>>(hbuf, wt_fc1, fc1b, nullptr, hf, 8192, 4096, 1024);
  gemm_bt<1, float><<<dim3(512), 256, 0, stream>>>(hf, wt_fc2, fc2b, x1, out, 8192, 1024, 4096);
}